// Round 1
// baseline (413.011 us; speedup 1.0000x reference)
//
#include <hip/hip_runtime.h>
#include <math.h>

#define BB 512
#define TT 512
#define OO 64

// One block per batch element. 256 threads = 64 tags (j) x 4 i-chunks (c) of 16.
// Forward Viterbi scan with backpointers (u8) and quantized confidences (u8)
// kept entirely in LDS; fused backtrack by thread 0 at the end.
__global__ __launch_bounds__(256) void crf_decode_kernel(
    const float* __restrict__ logits,   // [B][T][O]
    const float* __restrict__ trans,    // [O][O]
    const int*   __restrict__ seqlens,  // [B]
    float* __restrict__ out)            // [2][B][T]: tags(as float) then scores
{
    const int b   = blockIdx.x;
    const int tid = threadIdx.x;
    const int j   = tid >> 2;   // tag index 0..63
    const int c   = tid & 3;    // i-chunk 0..3 (i = c*16 .. c*16+15)

    __shared__ unsigned char bpl[TT][OO];   // backpointers, rows 1..L-1 used
    __shared__ unsigned char scl[TT][OO];   // quantized confidences
    __shared__ float st[2][OO];             // ping-pong state

    const int L = seqlens[b];
    const float* lg = logits + (size_t)b * TT * OO;

    // Preload this thread's transition column chunk: trc[i2] = trans[c*16+i2][j]
    float trc[16];
    #pragma unroll
    for (int i2 = 0; i2 < 16; ++i2)
        trc[i2] = trans[(c * 16 + i2) * OO + j];

    // init state = logits[b][0][:]
    if (tid < OO) st[0][tid] = lg[tid];
    __syncthreads();

    int cur = 0;
    for (int t = 1; t < L; ++t) {
        // emission for this tag (only c==0 lane uses it; issued early to hide latency)
        float x = lg[t * OO + j];

        float v[16];
        float m = -1e30f;
        int   idx = 0;
        #pragma unroll
        for (int i2 = 0; i2 < 16; ++i2) {
            float val = st[cur][c * 16 + i2] + trc[i2];
            v[i2] = val;
            if (val > m) { m = val; idx = c * 16 + i2; }   // first-max semantics
        }
        // reduce (m, idx) over the 4 chunk lanes; ties -> smaller i (matches jnp.argmax)
        #pragma unroll
        for (int d = 1; d <= 2; d <<= 1) {
            float mo = __shfl_xor(m, d);
            int   io = __shfl_xor(idx, d);
            if (mo > m || (mo == m && io < idx)) { m = mo; idx = io; }
        }
        // sum of exp(val - m)
        float s = 0.f;
        #pragma unroll
        for (int i2 = 0; i2 < 16; ++i2)
            s += __expf(v[i2] - m);
        #pragma unroll
        for (int d = 1; d <= 2; d <<= 1)
            s += __shfl_xor(s, d);

        if (c == 0) {
            st[cur ^ 1][j] = x + m;
            bpl[t][j] = (unsigned char)idx;
            float conf = 1.0f / s;                       // = max softmax prob
            conf = fminf(conf, 1.0f);
            scl[t][j] = (unsigned char)(conf * 255.0f + 0.5f);
        }
        cur ^= 1;
        __syncthreads();
    }

    // Epilogue: final argmax + confidence, then backtrack (thread 0, LDS-resident chain)
    if (tid == 0) {
        float m = -1e30f; int idx = 0;
        for (int jj = 0; jj < OO; ++jj) {
            float vv = st[cur][jj];
            if (vv > m) { m = vv; idx = jj; }
        }
        float s = 0.f;
        for (int jj = 0; jj < OO; ++jj)
            s += __expf(st[cur][jj] - m);

        float* out_tags   = out + (size_t)b * TT;
        float* out_scores = out + (size_t)BB * TT + (size_t)b * TT;
        out_tags[L - 1]   = (float)idx;
        out_scores[L - 1] = 1.0f / s;

        int tag = idx;
        for (int t = L - 1; t >= 1; --t) {
            int ntag  = bpl[t][tag];
            float sc  = (float)scl[t][tag] * (1.0f / 255.0f);
            out_tags[t - 1]   = (float)ntag;
            out_scores[t - 1] = sc;
            tag = ntag;
        }
    }

    // zero the masked tail (harness poisons d_out once; we must write everything)
    float* out_tags   = out + (size_t)b * TT;
    float* out_scores = out + (size_t)BB * TT + (size_t)b * TT;
    for (int p = L + tid; p < TT; p += 256) {
        out_tags[p]   = 0.f;
        out_scores[p] = 0.f;
    }
}

extern "C" void kernel_launch(void* const* d_in, const int* in_sizes, int n_in,
                              void* d_out, int out_size, void* d_ws, size_t ws_size,
                              hipStream_t stream) {
    const float* logits = (const float*)d_in[0];
    const float* trans  = (const float*)d_in[1];
    const int*   lens   = (const int*)d_in[2];
    float* out = (float*)d_out;
    crf_decode_kernel<<<BB, 256, 0, stream>>>(logits, trans, lens, out);
}